// Round 4
// baseline (753.611 us; speedup 1.0000x reference)
//
#include <hip/hip_runtime.h>
#include <hip/hip_bf16.h>
#include <hip/hip_cooperative_groups.h>

namespace cg = cooperative_groups;

// FacePartGAT: dense-graph GATConv x2 + mean + fc on MI355X. ALL I/O fp32.
// e[i,j] = leaky_relu(t_i + s_j) => softmax aggregation factorizes after
// sorting sources by s_j (prefix/suffix tables + split-point lookup). Exact.
// Round 15: dispatch-boundary collapse (15 -> 5). The ~7-10us inter-node
// barrier (wave drain + L2 writeback/inv between RAW-dependent graph nodes)
// dominated: ~50us of work, 210us measured. Post-GEMM pipeline per layer
// (sort, passA, passB, passC, attend [, mean, fc]) is now ONE cooperative
// kernel with grid.sync() between phases. Phase bodies verbatim from R14;
// passC's two independent scans run concurrently on the two half-blocks.

#define NNODE 4096
#define CDIM 128
#define TW 132           // table width: 128 features + z at col 128
#define NEG 0.2f
#define CHUNK 32
#define NCHUNK 128       // NNODE / CHUNK
#define CGRID 512        // cooperative grid size

typedef __bf16 bf16x8 __attribute__((ext_vector_type(8)));
typedef float f32x4 __attribute__((ext_vector_type(4)));

__device__ __forceinline__ unsigned short f2b(float f) {
  unsigned int u = __float_as_uint(f);
  u += 0x7fffu + ((u >> 16) & 1u);  // RTNE
  return (unsigned short)(u >> 16);
}

// One kernel: [0,3072) convert x -> bf16; [3072,3168) W1 transpose;
// [3168,3184) W2 transpose; [3184,3216) zero s1/t1; [3216,3224) zero s2/t2.
__global__ __launch_bounds__(256) void prep_kernel(const float* __restrict__ x,
                                                   const float* __restrict__ W1,
                                                   const float* __restrict__ W2,
                                                   unsigned short* __restrict__ xb,
                                                   unsigned short* __restrict__ W1t,
                                                   unsigned short* __restrict__ W2t,
                                                   float* __restrict__ zs1,
                                                   float* __restrict__ zs2) {
  __shared__ float tile[64][65];
  int b = blockIdx.x, t = threadIdx.x;
  if (b < 3072) {  // convert x: 4096*768/4 quads
    int i = b * 256 + t;
    float4 v = ((const float4*)x)[i];
    ushort4 o;
    o.x = f2b(v.x); o.y = f2b(v.y); o.z = f2b(v.z); o.w = f2b(v.w);
    ((ushort4*)xb)[i] = o;
    return;
  }
  if (b >= 3184) {  // zero s/t accumulators
    float4 z = {0.f, 0.f, 0.f, 0.f};
    if (b < 3216) {
      ((float4*)zs1)[(b - 3184) * 256 + t] = z;       // s1+t1: 32768 floats
    } else {
      ((float4*)zs2)[(b - 3216) * 256 + t] = z;       // s2+t2: 8192 floats
    }
    return;
  }
  const float* W; unsigned short* Wt; int K, N, n0, k0;
  if (b < 3072 + 96) {  // W1 [768,512] -> W1t [512,768]
    int b2 = b - 3072; W = W1; Wt = W1t; K = 768; N = 512;
    n0 = (b2 & 7) * 64; k0 = (b2 >> 3) * 64;
  } else {              // W2 [512,128] -> W2t [128,512]
    int b3 = b - 3072 - 96; W = W2; Wt = W2t; K = 512; N = 128;
    n0 = (b3 & 1) * 64; k0 = (b3 >> 1) * 64;
  }
  for (int p = 0; p < 16; p++) {
    int e = p * 256 + t;
    int rr = e >> 6, cc = e & 63;
    tile[rr][cc] = W[(size_t)(k0 + rr) * N + n0 + cc];
  }
  __syncthreads();
  for (int p = 0; p < 16; p++) {
    int e = p * 256 + t;
    int rr = e >> 6, cc = e & 63;  // rr: n-dir, cc: k-dir
    Wt[(size_t)(n0 + rr) * K + k0 + cc] = f2b(tile[cc][rr]);
  }
}

// C[M,N] = A[M,K] x Bt[N,K]^T, both bf16 K-contig. BK=32, 256 thr = 4 waves
// (2x2). Register prefetch of tile k+1 between LDS barrier and MFMA.
// Fused epilogue: s[h][n] / t[h][n] partial dot products from acc registers
// (col-reduce over the 16-lane fm group, relaxed atomicAdd).
template <int BM, int BN>
__global__ __launch_bounds__(256) void mfma_gemm_bt(const unsigned short* __restrict__ A,
                                                    const unsigned short* __restrict__ Bt,
                                                    float* __restrict__ C,
                                                    int M, int N, int K,
                                                    float* __restrict__ sAcc,
                                                    float* __restrict__ tAcc,
                                                    const float* __restrict__ av_s,
                                                    const float* __restrict__ av_d) {
  __shared__ __align__(16) unsigned short As[BM * 40];
  __shared__ __align__(16) unsigned short Bs[BN * 40];
  constexpr int WM = BM / 2, WN = BN / 2;
  constexpr int FI = WM / 16, FJ = WN / 16;
  constexpr int EA = BM * 32 / 8;
  constexpr int EB = BN * 32 / 8;
  constexpr int NA = (EA + 255) / 256;
  constexpr int NB = (EB + 255) / 256;
  int tid = threadIdx.x;
  int lane = tid & 63, wave = tid >> 6;
  int wm = (wave >> 1) * WM, wn = (wave & 1) * WN;
  int m0 = blockIdx.y * BM, n0 = blockIdx.x * BN;
  int fm = lane & 15, fq = lane >> 4;
  f32x4 acc[FI][FJ] = {};
  uint4 ar[NA], br[NB];
  // preload tile 0
#pragma unroll
  for (int q = 0; q < NA; q++) {
    int e = q * 256 + tid;
    if (e < EA) {
      int r = e >> 2, kk = (e & 3) * 8;
      ar[q] = *(const uint4*)(A + (size_t)(m0 + r) * K + kk);
    }
  }
#pragma unroll
  for (int q = 0; q < NB; q++) {
    int e = q * 256 + tid;
    if (e < EB) {
      int r = e >> 2, kk = (e & 3) * 8;
      br[q] = *(const uint4*)(Bt + (size_t)(n0 + r) * K + kk);
    }
  }
  for (int k0 = 0; k0 < K; k0 += 32) {
    __syncthreads();  // previous iter's ds_reads done before overwrite
#pragma unroll
    for (int q = 0; q < NA; q++) {
      int e = q * 256 + tid;
      if (e < EA) {
        int r = e >> 2, kk = (e & 3) * 8;
        *(uint4*)&As[r * 40 + kk] = ar[q];
      }
    }
#pragma unroll
    for (int q = 0; q < NB; q++) {
      int e = q * 256 + tid;
      if (e < EB) {
        int r = e >> 2, kk = (e & 3) * 8;
        *(uint4*)&Bs[r * 40 + kk] = br[q];
      }
    }
    __syncthreads();
    // prefetch tile k+1 (in flight during ds_read + MFMA below)
    if (k0 + 32 < K) {
#pragma unroll
      for (int q = 0; q < NA; q++) {
        int e = q * 256 + tid;
        if (e < EA) {
          int r = e >> 2, kk = (e & 3) * 8;
          ar[q] = *(const uint4*)(A + (size_t)(m0 + r) * K + k0 + 32 + kk);
        }
      }
#pragma unroll
      for (int q = 0; q < NB; q++) {
        int e = q * 256 + tid;
        if (e < EB) {
          int r = e >> 2, kk = (e & 3) * 8;
          br[q] = *(const uint4*)(Bt + (size_t)(n0 + r) * K + k0 + 32 + kk);
        }
      }
    }
    bf16x8 af[FI], bfr[FJ];
#pragma unroll
    for (int i = 0; i < FI; i++)
      af[i] = *(const bf16x8*)&As[(wm + i * 16 + fm) * 40 + fq * 8];
#pragma unroll
    for (int j = 0; j < FJ; j++)
      bfr[j] = *(const bf16x8*)&Bs[(wn + j * 16 + fm) * 40 + fq * 8];
#pragma unroll
    for (int i = 0; i < FI; i++)
#pragma unroll
      for (int j = 0; j < FJ; j++)
        acc[i][j] = __builtin_amdgcn_mfma_f32_16x16x32_bf16(af[i], bfr[j], acc[i][j], 0, 0, 0);
  }
  // C store
#pragma unroll
  for (int i = 0; i < FI; i++) {
#pragma unroll
    for (int j = 0; j < FJ; j++) {
      int r = m0 + wm + i * 16 + fq * 4;
      int ccol = n0 + wn + j * 16 + fm;
#pragma unroll
      for (int reg = 0; reg < 4; reg++)
        C[(size_t)(r + reg) * N + ccol] = acc[i][j][reg];
    }
  }
  // fused s/t epilogue
  {
    int hh = n0 >> 7;
    float avs[FJ], avd[FJ];
#pragma unroll
    for (int j = 0; j < FJ; j++) {
      int col = n0 + wn + j * 16 + fm;
      avs[j] = av_s[col];
      avd[j] = av_d[col];
    }
#pragma unroll
    for (int i = 0; i < FI; i++) {
#pragma unroll
      for (int reg = 0; reg < 4; reg++) {
        float sv = 0.f, tv = 0.f;
#pragma unroll
        for (int j = 0; j < FJ; j++) {
          sv = fmaf(acc[i][j][reg], avs[j], sv);
          tv = fmaf(acc[i][j][reg], avd[j], tv);
        }
#pragma unroll
        for (int o = 1; o < 16; o <<= 1) {
          sv += __shfl_xor(sv, o, 64);
          tv += __shfl_xor(tv, o, 64);
        }
        if (fm == 0) {
          int row = m0 + wm + i * 16 + fq * 4 + reg;
          atomicAdd(&sAcc[(size_t)hh * NNODE + row], sv);
          atomicAdd(&tAcc[(size_t)hh * NNODE + row], tv);
        }
      }
    }
  }
}

// ---- cooperative layer kernel: sort -> passA -> passB -> passC -> attend
// ---- [-> mean -> fc]. Shared-memory union across phases.
struct SmSort { float keys[NNODE]; int pc[8][32]; int qc[8][32]; };
struct SmA    { float eP[2][CHUNK]; float eM[2][CHUNK]; int ids[2][CHUNK]; };
struct SmC    { float hrow[CHUNK][CDIM]; float eP[CHUNK]; float eM[CHUNK]; int ids[CHUNK]; };
struct SmM    { float4 red[256]; };
struct SmF    { float tmp[256]; float m[CDIM]; };
union SmU { SmSort srt; SmA pa; SmC pc; SmM mp; SmF fc; };

template <int H, typename OUT, bool READOUT>
__global__ __launch_bounds__(256) void layer_coop(
    const float* __restrict__ h,
    const float* __restrict__ sv, const float* __restrict__ tvv,
    float* __restrict__ ss, int* __restrict__ si, int* __restrict__ qlo,
    float* __restrict__ pP, float* __restrict__ pM,
    float* __restrict__ fP, float* __restrict__ fM,
    float* __restrict__ SS, float* __restrict__ PP,
    const float* __restrict__ bias, OUT* __restrict__ outp,
    const float* __restrict__ fcW, const float* __restrict__ fcb,
    float* __restrict__ mpart, float* __restrict__ fcout) {
  __shared__ __align__(16) SmU sm;
  cg::grid_group grid = cg::this_grid();
  int b = blockIdx.x, tid = threadIdx.x;
  constexpr int HC = H * CDIM;

  // ---- Phase S: rank sort + query-lo (verbatim R14 body) ----
  if (b < H * 128) {
    int hh = b >> 7, sb = b & 127;
    const float* sp = sv + (size_t)hh * NNODE;
    for (int k = tid; k < NNODE / 4; k += 256)
      ((float4*)sm.srt.keys)[k] = ((const float4*)sp)[k];
    __syncthreads();
    int slot = tid & 31, part = tid >> 5;
    int node = sb * 32 + slot;
    float mk = sm.srt.keys[node];
    float qk = -tvv[(size_t)hh * NNODE + node];
    int cnt = 0, cq = 0;
    int j0 = part * 512;
#pragma unroll 4
    for (int j = j0; j < j0 + 512; j += 4) {
      float4 kv = *(const float4*)&sm.srt.keys[j];
      cnt += (kv.x < mk) || (kv.x == mk && (j + 0) < node);
      cnt += (kv.y < mk) || (kv.y == mk && (j + 1) < node);
      cnt += (kv.z < mk) || (kv.z == mk && (j + 2) < node);
      cnt += (kv.w < mk) || (kv.w == mk && (j + 3) < node);
      cq += (kv.x < qk) + (kv.y < qk) + (kv.z < qk) + (kv.w < qk);
    }
    sm.srt.pc[part][slot] = cnt;
    sm.srt.qc[part][slot] = cq;
    __syncthreads();
    if (tid < 32) {
      int rank = 0;
#pragma unroll
      for (int p = 0; p < 8; p++) rank += sm.srt.pc[p][tid];
      int n2 = sb * 32 + tid;
      ss[(size_t)hh * NNODE + rank] = sm.srt.keys[n2];
      si[(size_t)hh * NNODE + rank] = n2;
    } else if (tid < 64) {
      int sl = tid - 32;
      int lo = 0;
#pragma unroll
      for (int p = 0; p < 8; p++) lo += sm.srt.qc[p][sl];
      qlo[(size_t)hh * NNODE + sb * 32 + sl] = lo;
    }
  }
  grid.sync();

  // ---- Phase A: chunk partial sums (2 chunks per block, half-split) ----
  if (b < H * (NCHUNK / 2)) {
    int half = tid >> 7, c = tid & 127;
    int hh = b / (NCHUNK / 2), pair = b % (NCHUNK / 2);
    int ci = pair * 2 + half;
    int base = ci * CHUNK;
    if (c < CHUNK) {
      float s0 = ss[(size_t)hh * NNODE + base + c];
      sm.pa.ids[half][c] = si[(size_t)hh * NNODE + base + c];
      sm.pa.eP[half][c] = expf(s0);
      sm.pa.eM[half][c] = expf(NEG * s0);
    }
    __syncthreads();
    float sp = 0.f, smm = 0.f;
    for (int kb = 0; kb < CHUNK; kb += 8) {
      float v[8];
#pragma unroll
      for (int j = 0; j < 8; j++)
        v[j] = h[(size_t)sm.pa.ids[half][kb + j] * HC + hh * CDIM + c];
#pragma unroll
      for (int j = 0; j < 8; j++) {
        sp = fmaf(sm.pa.eP[half][kb + j], v[j], sp);
        smm = fmaf(sm.pa.eM[half][kb + j], v[j], smm);
      }
    }
    size_t o = ((size_t)hh * NCHUNK + ci) * TW;
    pP[o + c] = sp;
    pM[o + c] = smm;
    if (c == 0) {
      float zp = 0.f, zm = 0.f;
#pragma unroll
      for (int k = 0; k < CHUNK; k++) { zp += sm.pa.eP[half][k]; zm += sm.pa.eM[half][k]; }
      pP[o + 128] = zp;
      pM[o + 128] = zm;
    }
  }
  grid.sync();

  // ---- Phase B: per-head exclusive prefix(M)/suffix(P) over chunk partials ----
  if (b < 2 * H && tid <= 128) {
    int hh = b >> 1, dir = b & 1;
    int c = tid;
    size_t base = (size_t)hh * NCHUNK * TW;
    if (dir == 0) {  // forward exclusive prefix of partM
      float run = 0.f;
      for (int g0 = 0; g0 < NCHUNK; g0 += 8) {
        float v[8];
#pragma unroll
        for (int j = 0; j < 8; j++) v[j] = pM[base + (size_t)(g0 + j) * TW + c];
#pragma unroll
        for (int j = 0; j < 8; j++) {
          fM[base + (size_t)(g0 + j) * TW + c] = run;
          run += v[j];
        }
      }
    } else {  // backward exclusive suffix of partP
      float run = 0.f;
      for (int g0 = NCHUNK - 8; g0 >= 0; g0 -= 8) {
        float v[8];
#pragma unroll
        for (int j = 7; j >= 0; j--) v[j] = pP[base + (size_t)(g0 + j) * TW + c];
#pragma unroll
        for (int j = 7; j >= 0; j--) {
          fP[base + (size_t)(g0 + j) * TW + c] = run;
          run += v[j];
        }
      }
    }
  }
  grid.sync();

  // ---- Phase C: table scans (M-prefix on half 0, P-suffix on half 1) ----
  if (b < H * NCHUNK) {
    int hh = b / NCHUNK, ci = b % NCHUNK;
    int c = tid & 127, half = tid >> 7;
    int base = ci * CHUNK;
    size_t hb = (size_t)hh * (NNODE + 1);
    if (tid < CHUNK) {
      float s0 = ss[(size_t)hh * NNODE + base + tid];
      sm.pc.ids[tid] = si[(size_t)hh * NNODE + base + tid];
      sm.pc.eP[tid] = expf(s0);
      sm.pc.eM[tid] = expf(NEG * s0);
    }
    __syncthreads();
    // gather h rows: half 0 loads rows 0..15, half 1 rows 16..31
    for (int kb = half * 16; kb < half * 16 + 16; kb += 8) {
      float v[8];
#pragma unroll
      for (int j = 0; j < 8; j++)
        v[j] = h[(size_t)sm.pc.ids[kb + j] * HC + hh * CDIM + c];
#pragma unroll
      for (int j = 0; j < 8; j++) sm.pc.hrow[kb + j][c] = v[j];
    }
    __syncthreads();
    size_t co = ((size_t)hh * NCHUNK + ci) * TW;
    if (half == 0) {  // M forward prefix
      float runm = fM[co + c];
      float runzm = (c == 0) ? fM[co + 128] : 0.f;
#pragma unroll 8
      for (int k = 0; k < CHUNK; k++) {
        size_t row = (hb + base + k) * TW;
        PP[row + c] = runm;
        if (c == 0) PP[row + 128] = runzm;
        runm = fmaf(sm.pc.eM[k], sm.pc.hrow[k][c], runm);
        runzm += sm.pc.eM[k];
      }
      if (ci == NCHUNK - 1) {
        size_t row = (hb + NNODE) * TW;
        PP[row + c] = runm;
        if (c == 0) PP[row + 128] = runzm;
      }
    } else {  // P backward suffix
      float runp = fP[co + c];
      float runzp = (c == 0) ? fP[co + 128] : 0.f;
#pragma unroll 8
      for (int k = CHUNK - 1; k >= 0; k--) {
        runp = fmaf(sm.pc.eP[k], sm.pc.hrow[k][c], runp);
        runzp += sm.pc.eP[k];
        size_t row = (hb + base + k) * TW;
        SS[row + c] = runp;
        if (c == 0) SS[row + 128] = runzp;
      }
      if (ci == NCHUNK - 1) {
        size_t row = (hb + NNODE) * TW;
        SS[row + c] = 0.f;
        if (c == 0) SS[row + 128] = 0.f;
      }
    }
  }
  grid.sync();

  // ---- Phase ATT: combine tables at precomputed split, +bias, ELU ----
  {
    constexpr int PER = (H * NNODE) / CGRID;  // 32 (H=4) or 8 (H=1)
    int half = tid >> 7, c = tid & 127;
#pragma unroll 2
    for (int it = 0; it < PER / 2; it++) {
      int o = b * PER + it * 2 + half;
      int n = o / H, hh = o % H;
      float tv = tvv[(size_t)hh * NNODE + n];
      int lo = qlo[(size_t)hh * NNODE + n];
      size_t hb = (size_t)hh * (NNODE + 1);
      float wp = expf(tv), wm = expf(NEG * tv);
      float num = wp * SS[(hb + lo) * TW + c] + wm * PP[(hb + lo) * TW + c];
      float Z = wp * SS[(hb + lo) * TW + 128] + wm * PP[(hb + lo) * TW + 128];
      float ov = num / Z + bias[hh * CDIM + c];
      float r = (ov > 0.f) ? ov : (expf(ov) - 1.f);
      if constexpr (sizeof(OUT) == 2)
        outp[(size_t)n * HC + hh * CDIM + c] = f2b(r);
      else
        outp[(size_t)n * HC + hh * CDIM + c] = r;
    }
  }

  if constexpr (READOUT) {
    grid.sync();
    // ---- Phase MEAN: coalesced column partial sums (64 active blocks) ----
    if (b < 64) {
      int q = tid & 31, r0 = tid >> 5;
      const float4* xp = (const float4*)outp;
      float4 s4 = {0.f, 0.f, 0.f, 0.f};
      int base = b * 64;
      for (int r = r0; r < 64; r += 8) {
        float4 v = xp[(size_t)(base + r) * 32 + q];
        s4.x += v.x; s4.y += v.y; s4.z += v.z; s4.w += v.w;
      }
      sm.mp.red[tid] = s4; __syncthreads();
      for (int off = 4; off > 0; off >>= 1) {
        if (r0 < off) {
          float4 o4 = sm.mp.red[tid + off * 32];
          sm.mp.red[tid].x += o4.x; sm.mp.red[tid].y += o4.y;
          sm.mp.red[tid].z += o4.z; sm.mp.red[tid].w += o4.w;
        }
        __syncthreads();
      }
      if (tid < 32) ((float4*)mpart)[b * 32 + tid] = sm.mp.red[tid];
    }
    grid.sync();
    // ---- Phase FC: reduce partials (redundant per block) + GEMV ----
    if (b < 3) {
      int c = tid & 127, hf = tid >> 7;
      float a = 0.f;
      for (int g = hf; g < 64; g += 2) a += mpart[g * CDIM + c];
      sm.fc.tmp[tid] = a; __syncthreads();
      if (tid < 128) sm.fc.m[tid] = (sm.fc.tmp[tid] + sm.fc.tmp[tid + 128]) * (1.f / NNODE);
      __syncthreads();
      int d = b * 256 + tid;  // 768 total
      float acc = fcb[d];
#pragma unroll 4
      for (int c2 = 0; c2 < CDIM; c2++) acc = fmaf(sm.fc.m[c2], fcW[c2 * 768 + d], acc);
      fcout[d] = acc;
    }
  }
}

extern "C" void kernel_launch(void* const* d_in, const int* in_sizes, int n_in,
                              void* d_out, int out_size, void* d_ws, size_t ws_size,
                              hipStream_t stream) {
  const float* x   = (const float*)d_in[0];
  const float* W1  = (const float*)d_in[1];
  const float* as1 = (const float*)d_in[2];
  const float* ad1 = (const float*)d_in[3];
  const float* b1  = (const float*)d_in[4];
  const float* W2  = (const float*)d_in[5];
  const float* as2 = (const float*)d_in[6];
  const float* ad2 = (const float*)d_in[7];
  const float* b2  = (const float*)d_in[8];
  const float* fcW = (const float*)d_in[9];
  const float* fcb = (const float*)d_in[10];

  float* ws = (float*)d_ws;
  size_t off = 0;
  auto alloc = [&](size_t nfloats) { float* p = ws + off; off += nfloats; return p; };

  float* h1  = alloc((size_t)NNODE * 512);
  float* x2f = alloc((size_t)NNODE * 256 + 64 + 16384);  // x2b bf16 + W2t bf16
  float* h2  = alloc((size_t)NNODE * 128);
  float* x3  = alloc((size_t)NNODE * 128);
  float* s1  = alloc((size_t)4 * NNODE);
  float* t1  = alloc((size_t)4 * NNODE);
  float* sS1 = alloc((size_t)4 * NNODE);
  int*   sI1 = (int*)alloc((size_t)4 * NNODE);
  int*   qL1 = (int*)alloc((size_t)4 * NNODE);
  float* SS1 = alloc((size_t)4 * (NNODE + 1) * TW);
  float* PP1 = alloc((size_t)4 * (NNODE + 1) * TW);
  float* pP1 = alloc((size_t)4 * NCHUNK * TW);
  float* pM1 = alloc((size_t)4 * NCHUNK * TW);
  float* fP1 = alloc((size_t)4 * NCHUNK * TW);   // suffix of P
  float* fM1 = alloc((size_t)4 * NCHUNK * TW);   // prefix of M
  float* s2  = alloc(NNODE);
  float* t2  = alloc(NNODE);
  float* sS2 = alloc(NNODE);
  int*   sI2 = (int*)alloc(NNODE);
  int*   qL2 = (int*)alloc(NNODE);
  float* SS2 = alloc((size_t)(NNODE + 1) * TW);
  float* PP2 = alloc((size_t)(NNODE + 1) * TW);
  float* pP2 = alloc((size_t)NCHUNK * TW);
  float* pM2 = alloc((size_t)NCHUNK * TW);
  float* fP2 = alloc((size_t)NCHUNK * TW);
  float* fM2 = alloc((size_t)NCHUNK * TW);
  float* mpart = alloc((size_t)64 * CDIM);  // mean partial sums

  // bf16 staging aliased into PP1/SS1 (first written by coop1's passC phase,
  // strictly after gemm1 last reads them — stream ordered).
  unsigned short* xb  = (unsigned short*)PP1;  // 4096x768 bf16 = 6.3 MB (< 8.65 MB)
  unsigned short* W1t = (unsigned short*)SS1;  // 512x768 bf16
  unsigned short* x2b = (unsigned short*)x2f;                       // 4096x512 bf16
  unsigned short* W2t = (unsigned short*)(x2f + NNODE * 256 + 64);  // 128x512 bf16
  float* dout = (float*)d_out;

  // Prep: convert x + transpose/cast W1, W2 + zero s/t accumulators
  prep_kernel<<<3224, 256, 0, stream>>>(x, W1, W2, xb, W1t, W2t, s1, s2);
  // Layer 1 GEMM (fused s/t epilogue)
  mfma_gemm_bt<64, 64><<<dim3(512 / 64, NNODE / 64), 256, 0, stream>>>(
      xb, W1t, h1, NNODE, 512, 768, s1, t1, as1, ad1);
  // Layer 1 pipeline: sort+passA+passB+passC+attend, one cooperative kernel
  {
    auto* kfn = layer_coop<4, unsigned short, false>;
    void* ka[] = {(void*)&h1, (void*)&s1, (void*)&t1, (void*)&sS1, (void*)&sI1,
                  (void*)&qL1, (void*)&pP1, (void*)&pM1, (void*)&fP1, (void*)&fM1,
                  (void*)&SS1, (void*)&PP1, (void*)&b1, (void*)&x2b,
                  (void*)&fcW, (void*)&fcb, (void*)&mpart, (void*)&dout};
    hipLaunchCooperativeKernel((const void*)kfn, dim3(CGRID), dim3(256), ka, 0, stream);
  }
  // Layer 2 GEMM (fused s/t epilogue)
  mfma_gemm_bt<32, 64><<<dim3(128 / 64, NNODE / 32), 256, 0, stream>>>(
      x2b, W2t, h2, NNODE, 128, 512, s2, t2, as2, ad2);
  // Layer 2 pipeline + readout: sort..attend + mean + fc, one coop kernel
  {
    auto* kfn = layer_coop<1, float, true>;
    void* ka[] = {(void*)&h2, (void*)&s2, (void*)&t2, (void*)&sS2, (void*)&sI2,
                  (void*)&qL2, (void*)&pP2, (void*)&pM2, (void*)&fP2, (void*)&fM2,
                  (void*)&SS2, (void*)&PP2, (void*)&b2, (void*)&x3,
                  (void*)&fcW, (void*)&fcb, (void*)&mpart, (void*)&dout};
    hipLaunchCooperativeKernel((const void*)kfn, dim3(CGRID), dim3(256), ka, 0, stream);
  }
}

// Round 5
// 203.971 us; speedup vs baseline: 3.6947x; 3.6947x over previous
//
#include <hip/hip_runtime.h>
#include <hip/hip_bf16.h>

// FacePartGAT: dense-graph GATConv x2 + mean + fc on MI355X. ALL I/O fp32.
// e[i,j] = leaky_relu(t_i + s_j) => softmax aggregation factorizes after
// sorting sources by s_j (prefix/suffix tables + split-point lookup). Exact.
// Round 16: revert R15's cooperative fusion (grid.sync = 50-70us/barrier on
// 8 non-coherent XCDs -> 354us kernels). Back to R14 structure, then:
//  - passA+passC fused (passAC): local-carry tables (scans start at 0);
//    attend adds the chunk carry from passB's fP/fM (L2-resident). The
//    chunk partials fall out of the scans for free. -2 dispatches, half
//    the random h-gathers, no carry chain in the scan kernel.
//  - attend: 2 queries per 256-thread block (ILP on the lo->row chain).

#define NNODE 4096
#define CDIM 128
#define TW 132           // table width: 128 features + z at col 128
#define NEG 0.2f
#define CHUNK 32
#define NCHUNK 128       // NNODE / CHUNK

typedef __bf16 bf16x8 __attribute__((ext_vector_type(8)));
typedef float f32x4 __attribute__((ext_vector_type(4)));

__device__ __forceinline__ unsigned short f2b(float f) {
  unsigned int u = __float_as_uint(f);
  u += 0x7fffu + ((u >> 16) & 1u);  // RTNE
  return (unsigned short)(u >> 16);
}

// One kernel: [0,3072) convert x -> bf16; [3072,3168) W1 transpose;
// [3168,3184) W2 transpose; [3184,3216) zero s1/t1; [3216,3224) zero s2/t2.
__global__ __launch_bounds__(256) void prep_kernel(const float* __restrict__ x,
                                                   const float* __restrict__ W1,
                                                   const float* __restrict__ W2,
                                                   unsigned short* __restrict__ xb,
                                                   unsigned short* __restrict__ W1t,
                                                   unsigned short* __restrict__ W2t,
                                                   float* __restrict__ zs1,
                                                   float* __restrict__ zs2) {
  __shared__ float tile[64][65];
  int b = blockIdx.x, t = threadIdx.x;
  if (b < 3072) {  // convert x: 4096*768/4 quads
    int i = b * 256 + t;
    float4 v = ((const float4*)x)[i];
    ushort4 o;
    o.x = f2b(v.x); o.y = f2b(v.y); o.z = f2b(v.z); o.w = f2b(v.w);
    ((ushort4*)xb)[i] = o;
    return;
  }
  if (b >= 3184) {  // zero s/t accumulators
    float4 z = {0.f, 0.f, 0.f, 0.f};
    if (b < 3216) {
      ((float4*)zs1)[(b - 3184) * 256 + t] = z;       // s1+t1: 32768 floats
    } else {
      ((float4*)zs2)[(b - 3216) * 256 + t] = z;       // s2+t2: 8192 floats
    }
    return;
  }
  const float* W; unsigned short* Wt; int K, N, n0, k0;
  if (b < 3072 + 96) {  // W1 [768,512] -> W1t [512,768]
    int b2 = b - 3072; W = W1; Wt = W1t; K = 768; N = 512;
    n0 = (b2 & 7) * 64; k0 = (b2 >> 3) * 64;
  } else {              // W2 [512,128] -> W2t [128,512]
    int b3 = b - 3072 - 96; W = W2; Wt = W2t; K = 512; N = 128;
    n0 = (b3 & 1) * 64; k0 = (b3 >> 1) * 64;
  }
  for (int p = 0; p < 16; p++) {
    int e = p * 256 + t;
    int rr = e >> 6, cc = e & 63;
    tile[rr][cc] = W[(size_t)(k0 + rr) * N + n0 + cc];
  }
  __syncthreads();
  for (int p = 0; p < 16; p++) {
    int e = p * 256 + t;
    int rr = e >> 6, cc = e & 63;  // rr: n-dir, cc: k-dir
    Wt[(size_t)(n0 + rr) * K + k0 + cc] = f2b(tile[cc][rr]);
  }
}

// C[M,N] = A[M,K] x Bt[N,K]^T, both bf16 K-contig. BK=32, 256 thr = 4 waves
// (2x2). Register prefetch of tile k+1 between LDS barrier and MFMA.
// Fused epilogue: s[h][n] / t[h][n] partial dot products from acc registers
// (col-reduce over the 16-lane fm group, atomicAdd).
template <int BM, int BN>
__global__ __launch_bounds__(256) void mfma_gemm_bt(const unsigned short* __restrict__ A,
                                                    const unsigned short* __restrict__ Bt,
                                                    float* __restrict__ C,
                                                    int M, int N, int K,
                                                    float* __restrict__ sAcc,
                                                    float* __restrict__ tAcc,
                                                    const float* __restrict__ av_s,
                                                    const float* __restrict__ av_d) {
  __shared__ __align__(16) unsigned short As[BM * 40];
  __shared__ __align__(16) unsigned short Bs[BN * 40];
  constexpr int WM = BM / 2, WN = BN / 2;
  constexpr int FI = WM / 16, FJ = WN / 16;
  constexpr int EA = BM * 32 / 8;
  constexpr int EB = BN * 32 / 8;
  constexpr int NA = (EA + 255) / 256;
  constexpr int NB = (EB + 255) / 256;
  int tid = threadIdx.x;
  int lane = tid & 63, wave = tid >> 6;
  int wm = (wave >> 1) * WM, wn = (wave & 1) * WN;
  int m0 = blockIdx.y * BM, n0 = blockIdx.x * BN;
  int fm = lane & 15, fq = lane >> 4;
  f32x4 acc[FI][FJ] = {};
  uint4 ar[NA], br[NB];
  // preload tile 0
#pragma unroll
  for (int q = 0; q < NA; q++) {
    int e = q * 256 + tid;
    if (e < EA) {
      int r = e >> 2, kk = (e & 3) * 8;
      ar[q] = *(const uint4*)(A + (size_t)(m0 + r) * K + kk);
    }
  }
#pragma unroll
  for (int q = 0; q < NB; q++) {
    int e = q * 256 + tid;
    if (e < EB) {
      int r = e >> 2, kk = (e & 3) * 8;
      br[q] = *(const uint4*)(Bt + (size_t)(n0 + r) * K + kk);
    }
  }
  for (int k0 = 0; k0 < K; k0 += 32) {
    __syncthreads();  // previous iter's ds_reads done before overwrite
#pragma unroll
    for (int q = 0; q < NA; q++) {
      int e = q * 256 + tid;
      if (e < EA) {
        int r = e >> 2, kk = (e & 3) * 8;
        *(uint4*)&As[r * 40 + kk] = ar[q];
      }
    }
#pragma unroll
    for (int q = 0; q < NB; q++) {
      int e = q * 256 + tid;
      if (e < EB) {
        int r = e >> 2, kk = (e & 3) * 8;
        *(uint4*)&Bs[r * 40 + kk] = br[q];
      }
    }
    __syncthreads();
    // prefetch tile k+1 (in flight during ds_read + MFMA below)
    if (k0 + 32 < K) {
#pragma unroll
      for (int q = 0; q < NA; q++) {
        int e = q * 256 + tid;
        if (e < EA) {
          int r = e >> 2, kk = (e & 3) * 8;
          ar[q] = *(const uint4*)(A + (size_t)(m0 + r) * K + k0 + 32 + kk);
        }
      }
#pragma unroll
      for (int q = 0; q < NB; q++) {
        int e = q * 256 + tid;
        if (e < EB) {
          int r = e >> 2, kk = (e & 3) * 8;
          br[q] = *(const uint4*)(Bt + (size_t)(n0 + r) * K + k0 + 32 + kk);
        }
      }
    }
    bf16x8 af[FI], bfr[FJ];
#pragma unroll
    for (int i = 0; i < FI; i++)
      af[i] = *(const bf16x8*)&As[(wm + i * 16 + fm) * 40 + fq * 8];
#pragma unroll
    for (int j = 0; j < FJ; j++)
      bfr[j] = *(const bf16x8*)&Bs[(wn + j * 16 + fm) * 40 + fq * 8];
#pragma unroll
    for (int i = 0; i < FI; i++)
#pragma unroll
      for (int j = 0; j < FJ; j++)
        acc[i][j] = __builtin_amdgcn_mfma_f32_16x16x32_bf16(af[i], bfr[j], acc[i][j], 0, 0, 0);
  }
  // C store
#pragma unroll
  for (int i = 0; i < FI; i++) {
#pragma unroll
    for (int j = 0; j < FJ; j++) {
      int r = m0 + wm + i * 16 + fq * 4;
      int ccol = n0 + wn + j * 16 + fm;
#pragma unroll
      for (int reg = 0; reg < 4; reg++)
        C[(size_t)(r + reg) * N + ccol] = acc[i][j][reg];
    }
  }
  // fused s/t epilogue
  {
    int hh = n0 >> 7;
    float avs[FJ], avd[FJ];
#pragma unroll
    for (int j = 0; j < FJ; j++) {
      int col = n0 + wn + j * 16 + fm;
      avs[j] = av_s[col];
      avd[j] = av_d[col];
    }
#pragma unroll
    for (int i = 0; i < FI; i++) {
#pragma unroll
      for (int reg = 0; reg < 4; reg++) {
        float sv = 0.f, tv = 0.f;
#pragma unroll
        for (int j = 0; j < FJ; j++) {
          sv = fmaf(acc[i][j][reg], avs[j], sv);
          tv = fmaf(acc[i][j][reg], avd[j], tv);
        }
#pragma unroll
        for (int o = 1; o < 16; o <<= 1) {
          sv += __shfl_xor(sv, o, 64);
          tv += __shfl_xor(tv, o, 64);
        }
        if (fm == 0) {
          int row = m0 + wm + i * 16 + fq * 4 + reg;
          atomicAdd(&sAcc[(size_t)hh * NNODE + row], sv);
          atomicAdd(&tAcc[(size_t)hh * NNODE + row], tv);
        }
      }
    }
  }
}

// One-kernel rank sort + query split precompute. All 4096 keys in LDS
// (16 KB). Block = 32 nodes x 8 scan-parts of 512 keys; partial counts
// combined in LDS; direct scatter of (key, idx) to sorted position.
// ALSO counts lo[n] = #{j : s_j < -t_n} (strict <, == lower_bound).
__global__ __launch_bounds__(256) void rank_sort_kernel(const float* __restrict__ s,
                                                        const float* __restrict__ t,
                                                        float* __restrict__ ss,
                                                        int* __restrict__ si,
                                                        int* __restrict__ qlo) {
  __shared__ __align__(16) float keys[NNODE];
  __shared__ int pc[8][32], qc[8][32];
  int hh = blockIdx.y, tid = threadIdx.x;
  const float* sp = s + (size_t)hh * NNODE;
  for (int k = tid; k < NNODE / 4; k += 256)
    ((float4*)keys)[k] = ((const float4*)sp)[k];
  __syncthreads();
  int slot = tid & 31, part = tid >> 5;
  int node = blockIdx.x * 32 + slot;
  float mk = keys[node];
  float qk = -t[(size_t)hh * NNODE + node];
  int cnt = 0, cq = 0;
  int j0 = part * 512;
#pragma unroll 4
  for (int j = j0; j < j0 + 512; j += 4) {
    float4 kv = *(const float4*)&keys[j];
    cnt += (kv.x < mk) || (kv.x == mk && (j + 0) < node);
    cnt += (kv.y < mk) || (kv.y == mk && (j + 1) < node);
    cnt += (kv.z < mk) || (kv.z == mk && (j + 2) < node);
    cnt += (kv.w < mk) || (kv.w == mk && (j + 3) < node);
    cq += (kv.x < qk) + (kv.y < qk) + (kv.z < qk) + (kv.w < qk);
  }
  pc[part][slot] = cnt;
  qc[part][slot] = cq;
  __syncthreads();
  if (tid < 32) {
    int rank = 0;
#pragma unroll
    for (int p = 0; p < 8; p++) rank += pc[p][tid];
    int n2 = blockIdx.x * 32 + tid;
    ss[(size_t)hh * NNODE + rank] = keys[n2];
    si[(size_t)hh * NNODE + rank] = n2;
  } else if (tid < 64) {
    int sl = tid - 32;
    int lo = 0;
#pragma unroll
    for (int p = 0; p < 8; p++) lo += qc[p][sl];
    qlo[(size_t)hh * NNODE + blockIdx.x * 32 + sl] = lo;
  }
}

// Fused passA+passC: gather h rows ONCE, dual LOCAL scans (tables start at
// zero carry; attend adds chunk carries). The chunk partial sums for passB
// fall out as the scans' final running values. z at col 128.
__global__ __launch_bounds__(128) void passAC_kernel(const float* __restrict__ h,
                                                     const float* __restrict__ ss,
                                                     const int* __restrict__ si,
                                                     float* __restrict__ partP,
                                                     float* __restrict__ partM,
                                                     float* __restrict__ SS,
                                                     float* __restrict__ PP, int H) {
  __shared__ float hrow[CHUNK][CDIM];  // 16 KB
  __shared__ float eP[CHUNK], eM[CHUNK];
  __shared__ int ids[CHUNK];
  int b = blockIdx.x, hh = b / NCHUNK, ci = b % NCHUNK;
  int c = threadIdx.x;
  int HC = H * CDIM;
  int base = ci * CHUNK;
  size_t hb = (size_t)hh * (NNODE + 1);
  if (c < CHUNK) {
    float sv = ss[(size_t)hh * NNODE + base + c];
    ids[c] = si[(size_t)hh * NNODE + base + c];
    eP[c] = expf(sv);
    eM[c] = expf(NEG * sv);
  }
  __syncthreads();
  // gather h rows once into LDS (batched, per-thread column)
  for (int kb = 0; kb < CHUNK; kb += 8) {
    float v[8];
#pragma unroll
    for (int j = 0; j < 8; j++)
      v[j] = h[(size_t)ids[kb + j] * HC + hh * CDIM + c];
#pragma unroll
    for (int j = 0; j < 8; j++) hrow[kb + j][c] = v[j];
  }
  // M forward local prefix (exclusive); final run == chunk partial for passB
  float runm = 0.f, runzm = 0.f;
#pragma unroll 8
  for (int k = 0; k < CHUNK; k++) {
    size_t row = (hb + base + k) * TW;
    PP[row + c] = runm;
    if (c == 0) PP[row + 128] = runzm;
    runm = fmaf(eM[k], hrow[k][c], runm);
    runzm += eM[k];
  }
  size_t o = ((size_t)hh * NCHUNK + ci) * TW;
  partM[o + c] = runm;
  if (c == 0) partM[o + 128] = runzm;
  if (ci == NCHUNK - 1) {
    size_t row = (hb + NNODE) * TW;
    PP[row + c] = runm;
    if (c == 0) PP[row + 128] = runzm;
  }
  // P backward local suffix (inclusive); final run == chunk partial
  float runp = 0.f, runzp = 0.f;
#pragma unroll 8
  for (int k = CHUNK - 1; k >= 0; k--) {
    runp = fmaf(eP[k], hrow[k][c], runp);
    runzp += eP[k];
    size_t row = (hb + base + k) * TW;
    SS[row + c] = runp;
    if (c == 0) SS[row + 128] = runzp;
  }
  partP[o + c] = runp;
  if (c == 0) partP[o + 128] = runzp;
  if (ci == NCHUNK - 1) {
    size_t row = (hb + NNODE) * TW;
    SS[row + c] = 0.f;
    if (c == 0) SS[row + 128] = 0.f;
  }
}

// Pass B: per-head exclusive prefix scan of partM (forward) and exclusive
// suffix scan of partP (backward) over the NCHUNK chunk partials, incl. z.
__global__ __launch_bounds__(192) void passB_kernel(const float* __restrict__ partP,
                                                    const float* __restrict__ partM,
                                                    float* __restrict__ sufP,
                                                    float* __restrict__ prefM) {
  int hh = blockIdx.y, dir = blockIdx.x;
  int c = threadIdx.x;
  if (c > 128) return;  // 129 cols: 128 features + z
  size_t base = (size_t)hh * NCHUNK * TW;
  if (dir == 0) {  // forward exclusive prefix of partM
    float run = 0.f;
    for (int g0 = 0; g0 < NCHUNK; g0 += 8) {
      float v[8];
#pragma unroll
      for (int j = 0; j < 8; j++) v[j] = partM[base + (size_t)(g0 + j) * TW + c];
#pragma unroll
      for (int j = 0; j < 8; j++) {
        prefM[base + (size_t)(g0 + j) * TW + c] = run;
        run += v[j];
      }
    }
  } else {  // backward exclusive suffix of partP
    float run = 0.f;
    for (int g0 = NCHUNK - 8; g0 >= 0; g0 -= 8) {
      float v[8];
#pragma unroll
      for (int j = 7; j >= 0; j--) v[j] = partP[base + (size_t)(g0 + j) * TW + c];
#pragma unroll
      for (int j = 7; j >= 0; j--) {
        sufP[base + (size_t)(g0 + j) * TW + c] = run;
        run += v[j];
      }
    }
  }
}

// Per (dest, head): local table row at precomputed split + chunk carry
// (fP/fM, L2-resident), +bias, ELU. 2 queries per 256-thread block.
template <typename OUT>
__global__ __launch_bounds__(256) void attend_kernel(const float* __restrict__ SS,
                                                     const float* __restrict__ PP,
                                                     const float* __restrict__ fP,
                                                     const float* __restrict__ fM,
                                                     const int* __restrict__ qlo,
                                                     const float* __restrict__ tt,
                                                     const float* __restrict__ bias,
                                                     OUT* __restrict__ out, int H) {
  int half = threadIdx.x >> 7, c = threadIdx.x & 127;
  int o = blockIdx.x * 2 + half;
  int n = o / H, hh = o % H;
  float tv = tt[(size_t)hh * NNODE + n];
  int lo = qlo[(size_t)hh * NNODE + n];
  int ci = lo >> 5;                      // CHUNK = 32
  if (ci > NCHUNK - 1) ci = NCHUNK - 1;  // lo == NNODE
  size_t hb = (size_t)hh * (NNODE + 1);
  size_t co = ((size_t)hh * NCHUNK + ci) * TW;
  float wp = expf(tv), wm = expf(NEG * tv);
  float num = wp * (SS[(hb + lo) * TW + c] + fP[co + c]) +
              wm * (PP[(hb + lo) * TW + c] + fM[co + c]);
  float Z = wp * (SS[(hb + lo) * TW + 128] + fP[co + 128]) +
            wm * (PP[(hb + lo) * TW + 128] + fM[co + 128]);
  float ov = num / Z + bias[hh * CDIM + c];
  float r = (ov > 0.f) ? ov : (expf(ov) - 1.f);
  if constexpr (sizeof(OUT) == 2)
    out[(size_t)n * (H * CDIM) + hh * CDIM + c] = f2b(r);
  else
    out[(size_t)n * (H * CDIM) + hh * CDIM + c] = r;
}

// Coalesced column partial sums: block b sums rows [b*64, b*64+64) into
// part[b][128]. float4 loads, LDS tree over row-groups. No atomics.
__global__ __launch_bounds__(256) void mean_part_kernel(const float* __restrict__ x,
                                                        float* __restrict__ part) {
  __shared__ float4 red[256];
  int b = blockIdx.x, tid = threadIdx.x;
  int q = tid & 31, r0 = tid >> 5;  // q: col quad (4 cols), r0: row group
  const float4* xp = (const float4*)x;
  float4 s = {0.f, 0.f, 0.f, 0.f};
  int base = b * 64;
  for (int r = r0; r < 64; r += 8) {
    float4 v = xp[(size_t)(base + r) * 32 + q];
    s.x += v.x; s.y += v.y; s.z += v.z; s.w += v.w;
  }
  red[tid] = s; __syncthreads();
  for (int off = 4; off > 0; off >>= 1) {
    if (r0 < off) {
      float4 o = red[tid + off * 32];
      red[tid].x += o.x; red[tid].y += o.y; red[tid].z += o.z; red[tid].w += o.w;
    }
    __syncthreads();
  }
  if (tid < 32) ((float4*)part)[b * 32 + tid] = red[tid];
}

// Reduce the 64x128 partials (redundantly per block, trivial) then GEMV.
__global__ __launch_bounds__(256) void fc_kernel(const float* __restrict__ part,
                                                 const float* __restrict__ fcW,
                                                 const float* __restrict__ fcb,
                                                 float* __restrict__ out) {
  __shared__ float tmp[256];
  __shared__ float m[CDIM];
  int tid = threadIdx.x;
  int c = tid & 127, half = tid >> 7;
  float a = 0.f;
  for (int g = half; g < 64; g += 2) a += part[g * CDIM + c];
  tmp[tid] = a; __syncthreads();
  if (tid < 128) m[tid] = (tmp[tid] + tmp[tid + 128]) * (1.f / NNODE);
  __syncthreads();
  int d = blockIdx.x * 256 + tid;  // 768 total
  float acc = fcb[d];
#pragma unroll 4
  for (int c2 = 0; c2 < CDIM; c2++) acc = fmaf(m[c2], fcW[c2 * 768 + d], acc);
  out[d] = acc;
}

extern "C" void kernel_launch(void* const* d_in, const int* in_sizes, int n_in,
                              void* d_out, int out_size, void* d_ws, size_t ws_size,
                              hipStream_t stream) {
  const float* x   = (const float*)d_in[0];
  const float* W1  = (const float*)d_in[1];
  const float* as1 = (const float*)d_in[2];
  const float* ad1 = (const float*)d_in[3];
  const float* b1  = (const float*)d_in[4];
  const float* W2  = (const float*)d_in[5];
  const float* as2 = (const float*)d_in[6];
  const float* ad2 = (const float*)d_in[7];
  const float* b2  = (const float*)d_in[8];
  const float* fcW = (const float*)d_in[9];
  const float* fcb = (const float*)d_in[10];

  float* ws = (float*)d_ws;
  size_t off = 0;
  auto alloc = [&](size_t nfloats) { float* p = ws + off; off += nfloats; return p; };

  float* h1  = alloc((size_t)NNODE * 512);
  float* x2f = alloc((size_t)NNODE * 256 + 64 + 16384);  // x2b bf16 + W2t bf16
  float* h2  = alloc((size_t)NNODE * 128);
  float* x3  = alloc((size_t)NNODE * 128);
  float* s1  = alloc((size_t)4 * NNODE);
  float* t1  = alloc((size_t)4 * NNODE);
  float* sS1 = alloc((size_t)4 * NNODE);
  int*   sI1 = (int*)alloc((size_t)4 * NNODE);
  int*   qL1 = (int*)alloc((size_t)4 * NNODE);
  float* SS1 = alloc((size_t)4 * (NNODE + 1) * TW);
  float* PP1 = alloc((size_t)4 * (NNODE + 1) * TW);
  float* pP1 = alloc((size_t)4 * NCHUNK * TW);
  float* pM1 = alloc((size_t)4 * NCHUNK * TW);
  float* fP1 = alloc((size_t)4 * NCHUNK * TW);   // chunk suffix of P
  float* fM1 = alloc((size_t)4 * NCHUNK * TW);   // chunk prefix of M
  float* s2  = alloc(NNODE);
  float* t2  = alloc(NNODE);
  float* sS2 = alloc(NNODE);
  int*   sI2 = (int*)alloc(NNODE);
  int*   qL2 = (int*)alloc(NNODE);
  float* SS2 = alloc((size_t)(NNODE + 1) * TW);
  float* PP2 = alloc((size_t)(NNODE + 1) * TW);
  float* pP2 = alloc((size_t)NCHUNK * TW);
  float* pM2 = alloc((size_t)NCHUNK * TW);
  float* fP2 = alloc((size_t)NCHUNK * TW);
  float* fM2 = alloc((size_t)NCHUNK * TW);
  float* mpart = alloc((size_t)64 * CDIM);  // mean partial sums

  // bf16 staging aliased into PP1/SS1 (first written by passAC1, strictly
  // after gemm1 last reads them — stream ordered).
  unsigned short* xb  = (unsigned short*)PP1;  // 4096x768 bf16 = 6.3 MB (< 8.65 MB)
  unsigned short* W1t = (unsigned short*)SS1;  // 512x768 bf16
  unsigned short* x2b = (unsigned short*)x2f;                       // 4096x512 bf16
  unsigned short* W2t = (unsigned short*)(x2f + NNODE * 256 + 64);  // 128x512 bf16

  // Prep: convert x + transpose/cast W1, W2 + zero s/t accumulators
  prep_kernel<<<3224, 256, 0, stream>>>(x, W1, W2, xb, W1t, W2t, s1, s2);
  // Layer 1 (fused s/t epilogue)
  mfma_gemm_bt<64, 64><<<dim3(512 / 64, NNODE / 64), 256, 0, stream>>>(
      xb, W1t, h1, NNODE, 512, 768, s1, t1, as1, ad1);
  rank_sort_kernel<<<dim3(NNODE / 32, 4), 256, 0, stream>>>(s1, t1, sS1, sI1, qL1);
  passAC_kernel<<<4 * NCHUNK, 128, 0, stream>>>(h1, sS1, sI1, pP1, pM1, SS1, PP1, 4);
  passB_kernel<<<dim3(2, 4), 192, 0, stream>>>(pP1, pM1, fP1, fM1);
  attend_kernel<unsigned short><<<NNODE * 4 / 2, 256, 0, stream>>>(
      SS1, PP1, fP1, fM1, qL1, t1, b1, x2b, 4);
  // Layer 2 (fused s/t epilogue)
  mfma_gemm_bt<32, 64><<<dim3(128 / 64, NNODE / 32), 256, 0, stream>>>(
      x2b, W2t, h2, NNODE, 128, 512, s2, t2, as2, ad2);
  rank_sort_kernel<<<dim3(NNODE / 32, 1), 256, 0, stream>>>(s2, t2, sS2, sI2, qL2);
  passAC_kernel<<<NCHUNK, 128, 0, stream>>>(h2, sS2, sI2, pP2, pM2, SS2, PP2, 1);
  passB_kernel<<<dim3(2, 1), 192, 0, stream>>>(pP2, pM2, fP2, fM2);
  attend_kernel<float><<<NNODE / 2, 256, 0, stream>>>(
      SS2, PP2, fP2, fM2, qL2, t2, b2, x3, 1);
  // Readout: coalesced mean partials + fc
  mean_part_kernel<<<64, 256, 0, stream>>>(x3, mpart);
  fc_kernel<<<3, 256, 0, stream>>>(mpart, fcW, fcb, (float*)d_out);
}